// Round 11
// baseline (383.299 us; speedup 1.0000x reference)
//
#include <hip/hip_runtime.h>
#include <math.h>

// Problem constants (fixed by reference: b=4, n=2048, d=1024, H=16, DH=64)
#define BB    4
#define NN    2048
#define DD    1024
#define HH    16
#define DHD   64
#define INNER 1024
// log2(10000)/16 for inv_freq = 2^(-f * LOG2_10K_D16)
#define LOG2_10K_D16 0.8304820237218406f
// SCALE * log2(e): folded into Q at projection time -> attn uses raw exp2
#define SCALE_LOG2E 0.1803368801111601f

typedef short bf16x8 __attribute__((ext_vector_type(8)));   // 8 bf16 = 4 VGPRs
typedef short bf16x4 __attribute__((ext_vector_type(4)));   // 4 bf16 = 2 VGPRs
typedef float f32x4  __attribute__((ext_vector_type(4)));
typedef unsigned short u16x8 __attribute__((ext_vector_type(8)));

// async 16B/lane global->LDS (lane i lands at wave-uniform base + i*16)
#define ASYNC16(g, l) __builtin_amdgcn_global_load_lds( \
    (const __attribute__((address_space(1))) void*)(g),  \
    (__attribute__((address_space(3))) void*)(l), 16, 0, 0)

#define MFMA16(a, b, c) __builtin_amdgcn_mfma_f32_16x16x32_bf16((a), (b), (c), 0, 0, 0)

// ---------- fast exp2: raw v_exp_f32, no libm range guard ----------
static __device__ __forceinline__ float fexp2(float x) {
#if __has_builtin(__builtin_amdgcn_exp2f)
    return __builtin_amdgcn_exp2f(x);
#else
    float r;
    asm("v_exp_f32 %0, %1" : "=v"(r) : "v"(x));
    return r;
#endif
}

// ---------- bf16 helpers (manual RNE; no hip_bf16.h dependency) ----------
static __device__ __forceinline__ unsigned short f2bf(float f) {
    union { float f; unsigned int u; } v; v.f = f;
    unsigned int u = v.u;
    u += 0x7fffu + ((u >> 16) & 1u);
    return (unsigned short)(u >> 16);
}
// pack two f32 -> bf16x2 dword, round-half-up via +0x8000 then byte-perm.
static __device__ __forceinline__ unsigned int packbf2(float lo, float hi) {
    union { float f; unsigned int u; } a, b;
    a.f = lo; b.f = hi;
    return __builtin_amdgcn_perm(b.u + 0x8000u, a.u + 0x8000u, 0x07060302u);
}

// =====================================================================
// Pre-pass A: cast X fp32 -> bf16
// =====================================================================
__global__ __launch_bounds__(256) void cast_x_kernel(
    const float* __restrict__ X, unsigned short* __restrict__ Xb)
{
    const size_t i = ((size_t)blockIdx.x * 256 + threadIdx.x) * 8;
    const float4 a = *(const float4*)(X + i);
    const float4 b = *(const float4*)(X + i + 4);
    u16x8 o;
    o[0] = f2bf(a.x); o[1] = f2bf(a.y); o[2] = f2bf(a.z); o[3] = f2bf(a.w);
    o[4] = f2bf(b.x); o[5] = f2bf(b.y); o[6] = f2bf(b.z); o[7] = f2bf(b.w);
    *(u16x8*)(Xb + i) = o;
}

// =====================================================================
// Pre-pass B: transpose-cast W [K][N] fp32 -> Wt [N][K] bf16
// =====================================================================
__global__ __launch_bounds__(256) void tcast_kernel(
    const float* __restrict__ src, unsigned short* __restrict__ dst,
    int K, int N)
{
    __shared__ float ts[32][33];
    const int t = threadIdx.x;
    const int n0 = blockIdx.x * 32, k0 = blockIdx.y * 32;
    const int r = t >> 5, c = t & 31;
    #pragma unroll
    for (int p = 0; p < 4; ++p)
        ts[r + p * 8][c] = src[(size_t)(k0 + r + p * 8) * N + n0 + c];
    __syncthreads();
    #pragma unroll
    for (int p = 0; p < 4; ++p)
        dst[(size_t)(n0 + r + p * 8) * K + k0 + c] = f2bf(ts[c][r + p * 8]);
}

// =====================================================================
// Kernel 1: QKV projection via bf16 MFMA + fused RoPE + head-split.
// =====================================================================
__global__ __launch_bounds__(256) void proj_qkv_mfma(
    const unsigned short* __restrict__ Xb, const unsigned short* __restrict__ Wt,
    unsigned short* __restrict__ qb, unsigned short* __restrict__ kb,
    unsigned short* __restrict__ vb)
{
    __shared__ __align__(16) unsigned short As[128 * 32];
    __shared__ __align__(16) unsigned short Bs[128 * 32];

    const int t     = threadIdx.x;
    const int w     = t >> 6, lane = t & 63;
    const int lane4 = lane & 15, quad = lane >> 4, quad8 = quad * 8;
    const int wm    = w >> 1, wn = w & 1;
    const int m0    = blockIdx.y * 128, n0 = blockIdx.x * 128;

    const int srow = t >> 2, scol = (t & 3) * 8;
    const unsigned short* gA = Xb + (size_t)(m0 + srow) * DD + scol;
    const unsigned short* gB = Wt + (size_t)(n0 + srow) * DD + scol;
    unsigned short* lA = As + t * 8;
    unsigned short* lB = Bs + t * 8;

    f32x4 acc[4][4] = {};

    for (int k0 = 0; k0 < DD; k0 += 32) {
        __syncthreads();
        ASYNC16(gA + k0,            lA);
        ASYNC16(gA + 64 * DD + k0,  lA + 2048);
        ASYNC16(gB + k0,            lB);
        ASYNC16(gB + 64 * DD + k0,  lB + 2048);
        __syncthreads();

        bf16x8 a[4], b[4];
        #pragma unroll
        for (int i = 0; i < 4; ++i)
            a[i] = *(const bf16x8*)&As[(wm * 64 + i * 16 + lane4) * 32 + quad8];
        #pragma unroll
        for (int j = 0; j < 4; ++j)
            b[j] = *(const bf16x8*)&Bs[(wn * 64 + j * 16 + lane4) * 32 + quad8];
        #pragma unroll
        for (int i = 0; i < 4; ++i)
            #pragma unroll
            for (int j = 0; j < 4; ++j)
                acc[i][j] = MFMA16(a[i], b[j], acc[i][j]);
    }

    // ---- epilogue ----
    const int sec = n0 >> 10;                  // 0=q 1=k 2=v (uniform/block)

    if (sec == 2) {
        // V: transposed global layout, 4 consecutive n per lane -> uint2
        #pragma unroll
        for (int j = 0; j < 4; ++j) {
            const int csec = (n0 & 1023) + wn * 64 + j * 16;
            const int h    = csec >> 6;
            const int dh   = (csec & 63) + lane4;
            #pragma unroll
            for (int i = 0; i < 4; ++i) {
                const int rg0 = m0 + wm * 64 + i * 16 + quad * 4;
                const int b   = rg0 >> 11;
                const int n   = rg0 & 2047;
                uint2 pk;
                pk.x = packbf2(acc[i][j][0], acc[i][j][1]);
                pk.y = packbf2(acc[i][j][2], acc[i][j][3]);
                *(uint2*)(vb + (((size_t)b * HH + h) * DHD + dh) * NN + n) = pk;
            }
        }
    } else {
        unsigned short* dst = (sec == 0) ? qb : kb;
        const float qscale = (sec == 0) ? SCALE_LOG2E : 1.0f;
        #pragma unroll
        for (int j = 0; j < 4; ++j) {
            const int csec = (n0 & 1023) + wn * 64 + j * 16;
            const int h    = csec >> 6;
            const int dhb  = csec & 63;
            const int dh   = dhb + lane4;
            const bool rope = (dhb < 32);          // wave-uniform
            const float invf = fexp2(-(float)(dh >> 1) * LOG2_10K_D16);
            #pragma unroll
            for (int i = 0; i < 4; ++i) {
                #pragma unroll
                for (int r = 0; r < 4; ++r) {
                    const int rg = m0 + wm * 64 + i * 16 + quad * 4 + r;
                    const int b  = rg >> 11;
                    const int n  = rg & 2047;
                    float x = acc[i][j][r] * qscale;
                    if (rope) {
                        const float ang = (float)n * invf;
                        float s_, c_;
                        __sincosf(ang, &s_, &c_);
                        const float p = __shfl_xor(x, 1);
                        x = (lane4 & 1) ? fmaf(p, s_, x * c_)
                                        : fmaf(p, -s_, x * c_);
                    }
                    dst[(((size_t)b * HH + h) * NN + n) * DHD + dh] = f2bf(x);
                }
            }
        }
    }
}

// =====================================================================
// Kernel 2: flash attention, KEY-SPLIT waves, ZERO main-loop LDS (R10,
// resubmitted R11 -- R10 bench was an infra container failure, no signal).
// R4-R9 census: LDS pipe was the top consumer (~50% of CU cycles:
// 64 KB/block-iter + 33k conflict cyc/CU) -- and every wave consumed
// only data IT staged (wave-private since R5). The LDS round-trip is
// pure overhead: both fragment patterns load DIRECTLY from global in
// MFMA layout:
//   K A-frag: 16 rows x 64 B contiguous segments (full cache lines).
//   V A-frag: slot quad*8+e == key kq*16+quad*4+e (lo4) / +64 (hi4)
//     [verified identical to the R4-R9 staged permutation], i.e. two
//     b64 loads per av[d] (32-B segments).
// R2's failure causes all addressed: key-split => zero cross-wave
// redundancy; loads prefetched one FULL tile ahead into NAMED register
// sets (unroll-by-2, no runtime indexing); K/V XCD-pinned L2-resident
// (~200 cyc << ~700 cyc compute distance). No barriers, no LDS in the
// main loop; LDS only for the one-shot epilogue overlay. l via f32
// VALU sums (R8-proven) -> -4 MFMA/iter, -20 regs (fits (256,2)).
// =====================================================================
__global__ __launch_bounds__(256, 2) void attn_kernel(
    const unsigned short* __restrict__ qb, const unsigned short* __restrict__ kb,
    const unsigned short* __restrict__ vtb, unsigned short* __restrict__ aob)
{
    __shared__ __align__(16) unsigned char smem[65536];   // epilogue overlay only

    const int t     = threadIdx.x;
    const int kq    = t >> 6;          // wave's key-quarter
    const int lane  = t & 63;
    const int lane4 = lane & 15;
    const int quad  = lane >> 4;
    const int quad8 = quad * 8;

    const int bid = blockIdx.x;
    const int bh  = bid & 63;          // id%8 = bh%8 -> per-XCD head groups
    const int q0  = (bid >> 6) * 64;
    const size_t hb = (size_t)bh * NN * DHD;

    // Q B-fragments for ALL 64 queries (held in registers whole kernel)
    bf16x8 qf[4][2];
    #pragma unroll
    for (int qt = 0; qt < 4; ++qt) {
        const unsigned short* qrow = qb + hb + (size_t)(q0 + qt * 16 + lane4) * DHD;
        qf[qt][0] = *(const bf16x8*)(qrow + quad8);
        qf[qt][1] = *(const bf16x8*)(qrow + 32 + quad8);
    }

    // direct-global fragment bases
    // K: A[row = key][k = dh]: row = kt*128 + sub*64 + kq*16 + lane4,
    //    col = quad8 (+32 for hi half)
    const unsigned short* kfb = kb + hb + (size_t)(kq * 16 + lane4) * DHD + quad8;
    // V: A[row = dh][k-slot quad*8+e]: lo4 = keys kq*16+quad*4+e,
    //    hi4 = +64 (derived from & matching the R4-R9 staged permutation)
    const unsigned short* vflo = vtb + hb + (size_t)lane4 * NN + kq * 16 + quad * 4;
    const unsigned short* vfhi = vflo + 64;

    f32x4 o[4][4];
    float lsum[4] = {0.f, 0.f, 0.f, 0.f};
    #pragma unroll
    for (int d = 0; d < 4; ++d)
        #pragma unroll
        for (int qt = 0; qt < 4; ++qt) o[d][qt] = (f32x4){0.f, 0.f, 0.f, 0.f};

    // named double register sets (rule #20: no runtime-indexed arrays)
    bf16x8 akA[2][2], akB[2][2];
    bf16x4 avloA[4], avhiA[4], avloB[4], avhiB[4];

#define LOADK(dst, kt) do {                                                      \
    dst[0][0] = *(const bf16x8*)(kfb + (size_t)((kt) * 128)      * DHD);         \
    dst[0][1] = *(const bf16x8*)(kfb + (size_t)((kt) * 128)      * DHD + 32);    \
    dst[1][0] = *(const bf16x8*)(kfb + (size_t)((kt) * 128 + 64) * DHD);         \
    dst[1][1] = *(const bf16x8*)(kfb + (size_t)((kt) * 128 + 64) * DHD + 32);    \
} while (0)

#define LOADV(dlo, dhi, kt) do {                                                 \
    _Pragma("unroll")                                                            \
    for (int d_ = 0; d_ < 4; ++d_) {                                             \
        dlo[d_] = *(const bf16x4*)(vflo + (size_t)d_ * 16 * NN + (kt) * 128);    \
        dhi[d_] = *(const bf16x4*)(vfhi + (size_t)d_ * 16 * NN + (kt) * 128);    \
    }                                                                            \
} while (0)

#define COMPUTE(ak, avlo, avhi) do {                                             \
    bf16x8 pb_[4];                                                               \
    _Pragma("unroll")                                                            \
    for (int qt_ = 0; qt_ < 4; ++qt_) {                                          \
        f32x4 z0 = (f32x4){0.f, 0.f, 0.f, 0.f};                                  \
        f32x4 z1 = (f32x4){0.f, 0.f, 0.f, 0.f};                                  \
        z0 = MFMA16(ak[0][0], qf[qt_][0], z0);                                   \
        z0 = MFMA16(ak[0][1], qf[qt_][1], z0);                                   \
        z1 = MFMA16(ak[1][0], qf[qt_][0], z1);                                   \
        z1 = MFMA16(ak[1][1], qf[qt_][1], z1);                                   \
        const float e00 = fexp2(z0[0]), e01 = fexp2(z0[1]);                      \
        const float e02 = fexp2(z0[2]), e03 = fexp2(z0[3]);                      \
        const float e10 = fexp2(z1[0]), e11 = fexp2(z1[1]);                      \
        const float e12 = fexp2(z1[2]), e13 = fexp2(z1[3]);                      \
        union { unsigned int u[4]; bf16x8 v; } pk_;                              \
        pk_.u[0] = packbf2(e00, e01);                                            \
        pk_.u[1] = packbf2(e02, e03);                                            \
        pk_.u[2] = packbf2(e10, e11);                                            \
        pk_.u[3] = packbf2(e12, e13);                                            \
        pb_[qt_] = pk_.v;                                                        \
        lsum[qt_] += ((e00 + e01) + (e02 + e03)) + ((e10 + e11) + (e12 + e13));  \
    }                                                                            \
    _Pragma("unroll")                                                            \
    for (int d_ = 0; d_ < 4; ++d_) {                                             \
        const bf16x8 av_ = __builtin_shufflevector(avlo[d_], avhi[d_],           \
                                                   0, 1, 2, 3, 4, 5, 6, 7);      \
        _Pragma("unroll")                                                        \
        for (int qt_ = 0; qt_ < 4; ++qt_)                                        \
            o[d_][qt_] = MFMA16(av_, pb_[qt_], o[d_][qt_]);                      \
    }                                                                            \
} while (0)

    // prologue: fragments for tile 0
    LOADK(akA, 0);
    LOADV(avloA, avhiA, 0);

    for (int kt = 0; kt < NN / 128; kt += 2) {
        // prefetch tile kt+1 into B-set (latency hides under COMPUTE A)
        LOADK(akB, kt + 1);
        LOADV(avloB, avhiB, kt + 1);
        COMPUTE(akA, avloA, avhiA);
        // prefetch tile kt+2 into A-set (if any), then compute B
        if (kt + 2 < NN / 128) {
            LOADK(akA, kt + 2);
            LOADV(avloA, avhiA, kt + 2);
        }
        COMPUTE(akB, avloB, avhiB);
    }

#undef LOADK
#undef LOADV
#undef COMPUTE

    // ---- cross-quad l reduce (each quad summed its own key-subsets) ----
    #pragma unroll
    for (int qt = 0; qt < 4; ++qt) {
        float v = lsum[qt];
        v += __shfl_xor(v, 16);
        v += __shfl_xor(v, 32);
        lsum[qt] = v;          // full l over this wave's keys, all lanes
    }

    // ---- epilogue: cross-wave O reduction via LDS overlay ----
    float* pbuf = (float*)smem;   // [w][dh 64][q 64] f32 = 64 KB
    #pragma unroll
    for (int d = 0; d < 4; ++d)
        #pragma unroll
        for (int qt = 0; qt < 4; ++qt)
            #pragma unroll
            for (int r = 0; r < 4; ++r)
                pbuf[(kq * 64 + d * 16 + quad * 4 + r) * 64 + qt * 16 + lane4] = o[d][qt][r];
    __syncthreads();

    // wave kq finalizes q-tile kq (all dh)
    f32x4 of[4];
    #pragma unroll
    for (int d = 0; d < 4; ++d)
        #pragma unroll
        for (int r = 0; r < 4; ++r) {
            const int dh = d * 16 + quad * 4 + r;
            const int qc = kq * 16 + lane4;
            of[d][r] = pbuf[dh * 64 + qc] + pbuf[(64 + dh) * 64 + qc]
                     + pbuf[(128 + dh) * 64 + qc] + pbuf[(192 + dh) * 64 + qc];
        }
    __syncthreads();

    // l exchange (reuse first 1 KB of the overlay after O is consumed)
    if (quad == 0) {
        #pragma unroll
        for (int qt = 0; qt < 4; ++qt)
            pbuf[(kq * 4 + qt) * 16 + lane4] = lsum[qt];
    }
    __syncthreads();
    const float lt = pbuf[(0 * 4 + kq) * 16 + lane4] + pbuf[(1 * 4 + kq) * 16 + lane4]
                   + pbuf[(2 * 4 + kq) * 16 + lane4] + pbuf[(3 * 4 + kq) * 16 + lane4];
    const float linv = 1.0f / lt;

    const int b = bh >> 4, h = bh & 15;
    const int n = q0 + kq * 16 + lane4;
    unsigned short* obase = aob + ((size_t)b * NN + n) * INNER + h * DHD;
    #pragma unroll
    for (int d = 0; d < 4; ++d) {
        uint2 pk;
        pk.x = packbf2(of[d][0] * linv, of[d][1] * linv);
        pk.y = packbf2(of[d][2] * linv, of[d][3] * linv);
        *(uint2*)(obase + d * 16 + quad * 4) = pk;
    }
}

// =====================================================================
// Kernel 3: output projection via bf16 MFMA.
// =====================================================================
__global__ __launch_bounds__(256) void out_proj_mfma(
    const unsigned short* __restrict__ Ab, const unsigned short* __restrict__ Wt,
    const float* __restrict__ bias, float* __restrict__ C)
{
    __shared__ __align__(16) unsigned short As[128 * 32];
    __shared__ __align__(16) unsigned short Bs[128 * 32];

    const int t     = threadIdx.x;
    const int w     = t >> 6, lane = t & 63;
    const int lane4 = lane & 15, quad = lane >> 4, quad8 = quad * 8;
    const int wm    = w >> 1, wn = w & 1;
    const int m0    = blockIdx.y * 128, n0 = blockIdx.x * 128;

    const int srow = t >> 2, scol = (t & 3) * 8;
    const unsigned short* gA = Ab + (size_t)(m0 + srow) * INNER + scol;
    const unsigned short* gB = Wt + (size_t)(n0 + srow) * INNER + scol;
    unsigned short* lA = As + t * 8;
    unsigned short* lB = Bs + t * 8;

    f32x4 acc[4][4] = {};

    for (int k0 = 0; k0 < INNER; k0 += 32) {
        __syncthreads();
        ASYNC16(gA + k0,               lA);
        ASYNC16(gA + 64 * INNER + k0,  lA + 2048);
        ASYNC16(gB + k0,               lB);
        ASYNC16(gB + 64 * INNER + k0,  lB + 2048);
        __syncthreads();

        bf16x8 a[4], b[4];
        #pragma unroll
        for (int i = 0; i < 4; ++i)
            a[i] = *(const bf16x8*)&As[(wm * 64 + i * 16 + lane4) * 32 + quad8];
        #pragma unroll
        for (int j = 0; j < 4; ++j)
            b[j] = *(const bf16x8*)&Bs[(wn * 64 + j * 16 + lane4) * 32 + quad8];
        #pragma unroll
        for (int i = 0; i < 4; ++i)
            #pragma unroll
            for (int j = 0; j < 4; ++j)
                acc[i][j] = MFMA16(a[i], b[j], acc[i][j]);
    }

    #pragma unroll
    for (int j = 0; j < 4; ++j) {
        const int col = n0 + wn * 64 + j * 16 + lane4;
        const float bv = bias[col];
        #pragma unroll
        for (int i = 0; i < 4; ++i)
            #pragma unroll
            for (int r = 0; r < 4; ++r) {
                const int rg = m0 + wm * 64 + i * 16 + quad * 4 + r;
                C[(size_t)rg * DD + col] = acc[i][j][r] + bv;
            }
    }
}

// =====================================================================
extern "C" void kernel_launch(void* const* d_in, const int* in_sizes, int n_in,
                              void* d_out, int out_size, void* d_ws, size_t ws_size,
                              hipStream_t stream)
{
    const float* X    = (const float*)d_in[0];   // (4,2048,1024)
    const float* Wq   = (const float*)d_in[1];   // (1024,1024)
    const float* Wkv  = (const float*)d_in[2];   // (1024,2048)
    const float* Wout = (const float*)d_in[3];   // (1024,1024)
    const float* bout = (const float*)d_in[4];   // (1024,)
    float* out = (float*)d_out;

    // ws (bf16 elems): qb|kb|vtb|xb(=aob after proj)|WtAll|WoT = 75.5 MB
    const size_t E = (size_t)BB * HH * NN * DHD;   // 8388608
    unsigned short* qb  = (unsigned short*)d_ws;
    unsigned short* kb  = qb + E;
    unsigned short* vtb = kb + E;                // V^T [b][h][dh][n]
    unsigned short* xb  = vtb + E;               // X bf16; later reused as ao
    unsigned short* wt  = xb + E;                // [3072][1024] = WqT ; WkvT
    unsigned short* wo  = wt + (size_t)3072 * 1024;  // [1024][1024]

    cast_x_kernel<<<4096, 256, 0, stream>>>(X, xb);
    tcast_kernel<<<dim3(32, 32), 256, 0, stream>>>(Wq,   wt,               1024, 1024);
    tcast_kernel<<<dim3(64, 32), 256, 0, stream>>>(Wkv,  wt + 1024 * 1024, 1024, 2048);
    tcast_kernel<<<dim3(32, 32), 256, 0, stream>>>(Wout, wo,               1024, 1024);

    proj_qkv_mfma<<<dim3(3072 / 128, 8192 / 128), 256, 0, stream>>>(
        xb, wt, qb, kb, vtb);

    attn_kernel<<<dim3(NN / 64 * BB * HH), 256, 0, stream>>>(qb, kb, vtb, xb);

    out_proj_mfma<<<dim3(1024 / 128, 8192 / 128), 256, 0, stream>>>(
        xb, wo, bout, out);
}

// Round 12
// 305.430 us; speedup vs baseline: 1.2550x; 1.2550x over previous
//
#include <hip/hip_runtime.h>
#include <math.h>

// Problem constants (fixed by reference: b=4, n=2048, d=1024, H=16, DH=64)
#define BB    4
#define NN    2048
#define DD    1024
#define HH    16
#define DHD   64
#define INNER 1024
// log2(10000)/16 for inv_freq = 2^(-f * LOG2_10K_D16)
#define LOG2_10K_D16 0.8304820237218406f
// SCALE * log2(e): folded into Q at projection time -> attn uses raw exp2
#define SCALE_LOG2E 0.1803368801111601f

typedef short bf16x8 __attribute__((ext_vector_type(8)));   // 8 bf16 = 4 VGPRs
typedef short bf16x4 __attribute__((ext_vector_type(4)));   // 4 bf16 = 2 VGPRs
typedef float f32x4  __attribute__((ext_vector_type(4)));
typedef unsigned short u16x8 __attribute__((ext_vector_type(8)));

// async 16B/lane global->LDS (lane i lands at wave-uniform base + i*16)
#define ASYNC16(g, l) __builtin_amdgcn_global_load_lds( \
    (const __attribute__((address_space(1))) void*)(g),  \
    (__attribute__((address_space(3))) void*)(l), 16, 0, 0)

#define MFMA16(a, b, c) __builtin_amdgcn_mfma_f32_16x16x32_bf16((a), (b), (c), 0, 0, 0)

// ---------- fast exp2: raw v_exp_f32, no libm range guard ----------
static __device__ __forceinline__ float fexp2(float x) {
#if __has_builtin(__builtin_amdgcn_exp2f)
    return __builtin_amdgcn_exp2f(x);
#else
    float r;
    asm("v_exp_f32 %0, %1" : "=v"(r) : "v"(x));
    return r;
#endif
}

// ---------- bf16 helpers (manual RNE; no hip_bf16.h dependency) ----------
static __device__ __forceinline__ unsigned short f2bf(float f) {
    union { float f; unsigned int u; } v; v.f = f;
    unsigned int u = v.u;
    u += 0x7fffu + ((u >> 16) & 1u);
    return (unsigned short)(u >> 16);
}
// pack two f32 -> bf16x2 dword, round-half-up via +0x8000 then byte-perm.
static __device__ __forceinline__ unsigned int packbf2(float lo, float hi) {
    union { float f; unsigned int u; } a, b;
    a.f = lo; b.f = hi;
    return __builtin_amdgcn_perm(b.u + 0x8000u, a.u + 0x8000u, 0x07060302u);
}

// =====================================================================
// Pre-pass A: cast X fp32 -> bf16
// =====================================================================
__global__ __launch_bounds__(256) void cast_x_kernel(
    const float* __restrict__ X, unsigned short* __restrict__ Xb)
{
    const size_t i = ((size_t)blockIdx.x * 256 + threadIdx.x) * 8;
    const float4 a = *(const float4*)(X + i);
    const float4 b = *(const float4*)(X + i + 4);
    u16x8 o;
    o[0] = f2bf(a.x); o[1] = f2bf(a.y); o[2] = f2bf(a.z); o[3] = f2bf(a.w);
    o[4] = f2bf(b.x); o[5] = f2bf(b.y); o[6] = f2bf(b.z); o[7] = f2bf(b.w);
    *(u16x8*)(Xb + i) = o;
}

// =====================================================================
// Pre-pass B: transpose-cast W [K][N] fp32 -> Wt [N][K] bf16
// =====================================================================
__global__ __launch_bounds__(256) void tcast_kernel(
    const float* __restrict__ src, unsigned short* __restrict__ dst,
    int K, int N)
{
    __shared__ float ts[32][33];
    const int t = threadIdx.x;
    const int n0 = blockIdx.x * 32, k0 = blockIdx.y * 32;
    const int r = t >> 5, c = t & 31;
    #pragma unroll
    for (int p = 0; p < 4; ++p)
        ts[r + p * 8][c] = src[(size_t)(k0 + r + p * 8) * N + n0 + c];
    __syncthreads();
    #pragma unroll
    for (int p = 0; p < 4; ++p)
        dst[(size_t)(n0 + r + p * 8) * K + k0 + c] = f2bf(ts[c][r + p * 8]);
}

// =====================================================================
// Kernel 1: QKV projection via bf16 MFMA + fused RoPE + head-split.
// R12: T3-minimum 2-phase loop -- stage tile k0+32 into buf[cur^1]
// BEFORE computing tile k0 from buf[cur]; ONE barrier per K-step (its
// implicit vmcnt/lgkmcnt drain provides both RAW and WAR ordering).
// Removes the exposed global->LDS latency of the old
// barrier;stage;barrier;compute structure.
// =====================================================================
__global__ __launch_bounds__(256) void proj_qkv_mfma(
    const unsigned short* __restrict__ Xb, const unsigned short* __restrict__ Wt,
    unsigned short* __restrict__ qb, unsigned short* __restrict__ kb,
    unsigned short* __restrict__ vb)
{
    __shared__ __align__(16) unsigned short As[2][128 * 32];
    __shared__ __align__(16) unsigned short Bs[2][128 * 32];

    const int t     = threadIdx.x;
    const int w     = t >> 6, lane = t & 63;
    const int lane4 = lane & 15, quad = lane >> 4, quad8 = quad * 8;
    const int wm    = w >> 1, wn = w & 1;
    const int m0    = blockIdx.y * 128, n0 = blockIdx.x * 128;

    const int srow = t >> 2, scol = (t & 3) * 8;
    const unsigned short* gA = Xb + (size_t)(m0 + srow) * DD + scol;
    const unsigned short* gB = Wt + (size_t)(n0 + srow) * DD + scol;

    f32x4 acc[4][4] = {};

    // prologue: stage k0 = 0 into buf 0
    ASYNC16(gA,            As[0] + t * 8);
    ASYNC16(gA + 64 * DD,  As[0] + t * 8 + 2048);
    ASYNC16(gB,            Bs[0] + t * 8);
    ASYNC16(gB + 64 * DD,  Bs[0] + t * 8 + 2048);
    __syncthreads();

    for (int k0 = 0; k0 < DD; k0 += 32) {
        const int cur = (k0 >> 5) & 1;
        if (k0 + 32 < DD) {
            ASYNC16(gA + k0 + 32,            As[cur ^ 1] + t * 8);
            ASYNC16(gA + 64 * DD + k0 + 32,  As[cur ^ 1] + t * 8 + 2048);
            ASYNC16(gB + k0 + 32,            Bs[cur ^ 1] + t * 8);
            ASYNC16(gB + 64 * DD + k0 + 32,  Bs[cur ^ 1] + t * 8 + 2048);
        }

        bf16x8 a[4], b[4];
        #pragma unroll
        for (int i = 0; i < 4; ++i)
            a[i] = *(const bf16x8*)&As[cur][(wm * 64 + i * 16 + lane4) * 32 + quad8];
        #pragma unroll
        for (int j = 0; j < 4; ++j)
            b[j] = *(const bf16x8*)&Bs[cur][(wn * 64 + j * 16 + lane4) * 32 + quad8];
        #pragma unroll
        for (int i = 0; i < 4; ++i)
            #pragma unroll
            for (int j = 0; j < 4; ++j)
                acc[i][j] = MFMA16(a[i], b[j], acc[i][j]);

        __syncthreads();   // drains vmcnt: buf[cur^1] ready for next iter
    }

    // ---- epilogue ----
    const int sec = n0 >> 10;                  // 0=q 1=k 2=v (uniform/block)

    if (sec == 2) {
        // V: transposed global layout, 4 consecutive n per lane -> uint2
        #pragma unroll
        for (int j = 0; j < 4; ++j) {
            const int csec = (n0 & 1023) + wn * 64 + j * 16;
            const int h    = csec >> 6;
            const int dh   = (csec & 63) + lane4;
            #pragma unroll
            for (int i = 0; i < 4; ++i) {
                const int rg0 = m0 + wm * 64 + i * 16 + quad * 4;
                const int b   = rg0 >> 11;
                const int n   = rg0 & 2047;
                uint2 pk;
                pk.x = packbf2(acc[i][j][0], acc[i][j][1]);
                pk.y = packbf2(acc[i][j][2], acc[i][j][3]);
                *(uint2*)(vb + (((size_t)b * HH + h) * DHD + dh) * NN + n) = pk;
            }
        }
    } else {
        unsigned short* dst = (sec == 0) ? qb : kb;
        const float qscale = (sec == 0) ? SCALE_LOG2E : 1.0f;
        #pragma unroll
        for (int j = 0; j < 4; ++j) {
            const int csec = (n0 & 1023) + wn * 64 + j * 16;
            const int h    = csec >> 6;
            const int dhb  = csec & 63;
            const int dh   = dhb + lane4;
            const bool rope = (dhb < 32);          // wave-uniform
            const float invf = fexp2(-(float)(dh >> 1) * LOG2_10K_D16);
            #pragma unroll
            for (int i = 0; i < 4; ++i) {
                #pragma unroll
                for (int r = 0; r < 4; ++r) {
                    const int rg = m0 + wm * 64 + i * 16 + quad * 4 + r;
                    const int b  = rg >> 11;
                    const int n  = rg & 2047;
                    float x = acc[i][j][r] * qscale;
                    if (rope) {
                        const float ang = (float)n * invf;
                        float s_, c_;
                        __sincosf(ang, &s_, &c_);
                        const float p = __shfl_xor(x, 1);
                        x = (lane4 & 1) ? fmaf(p, s_, x * c_)
                                        : fmaf(p, -s_, x * c_);
                    }
                    dst[(((size_t)b * HH + h) * NN + n) * DHD + dh] = f2bf(x);
                }
            }
        }
    }
}

// =====================================================================
// Kernel 2: flash attention, KEY-SPLIT waves (R4-exact revert -- the
// best verified attn at 110.4 us / ~625 TF). R5-R11 established every
// other structural axis (barriers, buffering, occupancy, SW pipeline,
// LDS elimination) lands >= this. ~625 TF is within ~10% of the known
// plain-HIP structure ceiling scaled to D=64's 2x softmax density.
// Wave kq owns a key-quarter; Q frags for all 64 queries in regs; P
// stays in registers (S^T MFMA output IS the PV B-frag layout);
// cooperative double-buffered staging, ONE barrier per 128-key tile.
// XCD pinning: id%8 == bh%8 -> K/V L2-resident.
// =====================================================================
__global__ __launch_bounds__(256, 2) void attn_kernel(
    const unsigned short* __restrict__ qb, const unsigned short* __restrict__ kb,
    const unsigned short* __restrict__ vtb, unsigned short* __restrict__ aob)
{
    __shared__ __align__(16) unsigned char smem[65536];
    unsigned short (*ks)[128][64] = (unsigned short (*)[128][64])smem;          // 2x16KB
    unsigned short (*vs)[64][128] = (unsigned short (*)[64][128])(smem + 32768); // 2x16KB

    const int t     = threadIdx.x;
    const int kq    = t >> 6;          // wave's key-quarter
    const int lane  = t & 63;
    const int lane4 = lane & 15;
    const int quad  = lane >> 4;
    const int quad8 = quad * 8;
    const int l7    = lane4 & 7;

    const int bid = blockIdx.x;
    const int bh  = bid & 63;          // id%8 = bh%8 -> per-XCD head groups
    const int q0  = (bid >> 6) * 64;
    const size_t hb = (size_t)bh * NN * DHD;

    // Q B-fragments for ALL 64 queries (held in registers whole kernel)
    bf16x8 qf[4][2];
    #pragma unroll
    for (int qt = 0; qt < 4; ++qt) {
        const unsigned short* qrow = qb + hb + (size_t)(q0 + qt * 16 + lane4) * DHD;
        qf[qt][0] = *(const bf16x8*)(qrow + quad8);
        qf[qt][1] = *(const bf16x8*)(qrow + 32 + quad8);
    }

    // ones A-fragment for the l-accumulating MFMA
    bf16x8 onesf;
    #pragma unroll
    for (int j = 0; j < 8; ++j) onesf[j] = (short)0x3F80;

    // ---- staging geometry (all XOR swizzles are s-invariant) ----
    // K: chunk u=t+256s: row=(t>>3)+32s, gcol=(t&7)*8, slot'=(t&7)^((t>>3)&7)
    const int krow0 = t >> 3;
    const int kcol  = ((t & 7) ^ (krow0 & 7)) * 8;
    const unsigned short* kg = kb + hb + (size_t)krow0 * DHD + (t & 7) * 8;
    // V: chunk u=t+256s: row=(t>>4)+16s, m=t&15, gcol=m*8
    //    keys 8m..8m+7 -> permuted cols: slotA(e<4), slotB(e>=4), +sub*4
    const int vrow0 = t >> 4;
    const int vm    = t & 15;
    const int vr7   = vrow0 & 7;
    const int vcX   = (vm >> 1) & 3;
    const int vsub  = vm >> 3;
    const int vqA   = (2 * vm) & 3;
    const int vqB   = (2 * vm + 1) & 3;
    const int colA  = (((vcX * 4 + vqA) ^ vr7) * 8) + vsub * 4;
    const int colB  = (((vcX * 4 + vqB) ^ vr7) * 8) + vsub * 4;
    const unsigned short* vg = vtb + hb + (size_t)vrow0 * NN + vm * 8;

    f32x4 o[4][4], lacc[4];
    #pragma unroll
    for (int d = 0; d < 4; ++d)
        #pragma unroll
        for (int qt = 0; qt < 4; ++qt) o[d][qt] = (f32x4){0.f, 0.f, 0.f, 0.f};
    #pragma unroll
    for (int qt = 0; qt < 4; ++qt) lacc[qt] = (f32x4){0.f, 0.f, 0.f, 0.f};

    // ---- prologue: stage tile 0 into buf 0 ----
    {
        bf16x8 kv[4], vv[4];
        #pragma unroll
        for (int s = 0; s < 4; ++s) {
            kv[s] = *(const bf16x8*)(kg + (size_t)s * 32 * DHD);
            vv[s] = *(const bf16x8*)(vg + (size_t)s * 16 * NN);
        }
        #pragma unroll
        for (int s = 0; s < 4; ++s) {
            *(bf16x8*)&ks[0][krow0 + 32 * s][kcol] = kv[s];
            bf16x4 lo = __builtin_shufflevector(vv[s], vv[s], 0, 1, 2, 3);
            bf16x4 hi = __builtin_shufflevector(vv[s], vv[s], 4, 5, 6, 7);
            *(bf16x4*)&vs[0][vrow0 + 16 * s][colA] = lo;
            *(bf16x4*)&vs[0][vrow0 + 16 * s][colB] = hi;
        }
    }
    __syncthreads();

    for (int kt = 0; kt < NN / 128; ++kt) {
        const int cur = kt & 1;
        const bool more = (kt + 1 < NN / 128);

        // issue next tile's global loads (latency hides under compute)
        bf16x8 kv[4], vv[4];
        if (more) {
            #pragma unroll
            for (int s = 0; s < 4; ++s) {
                kv[s] = *(const bf16x8*)(kg + (size_t)(kt + 1) * 128 * DHD + (size_t)s * 32 * DHD);
                vv[s] = *(const bf16x8*)(vg + (kt + 1) * 128 + (size_t)s * 16 * NN);
            }
        }

        // ---- QK A-fragments: this wave's 16 keys per 64-key subtile ----
        bf16x8 ak[2][2];
        #pragma unroll
        for (int sub = 0; sub < 2; ++sub) {
            const int row = sub * 64 + kq * 16 + lane4;
            ak[sub][0] = *(const bf16x8*)&ks[cur][row][(quad ^ l7) * 8];
            ak[sub][1] = *(const bf16x8*)&ks[cur][row][((quad + 4) ^ l7) * 8];
        }

        // ---- S^T -> exp2 -> P B-frags, all in registers ----
        bf16x8 pb[4];
        #pragma unroll
        for (int qt = 0; qt < 4; ++qt) {
            f32x4 z0 = (f32x4){0.f, 0.f, 0.f, 0.f};
            f32x4 z1 = (f32x4){0.f, 0.f, 0.f, 0.f};
            z0 = MFMA16(ak[0][0], qf[qt][0], z0);
            z0 = MFMA16(ak[0][1], qf[qt][1], z0);
            z1 = MFMA16(ak[1][0], qf[qt][0], z1);
            z1 = MFMA16(ak[1][1], qf[qt][1], z1);
            union { unsigned int u[4]; bf16x8 v; } pk;
            pk.u[0] = packbf2(fexp2(z0[0]), fexp2(z0[1]));
            pk.u[1] = packbf2(fexp2(z0[2]), fexp2(z0[3]));
            pk.u[2] = packbf2(fexp2(z1[0]), fexp2(z1[1]));
            pk.u[3] = packbf2(fexp2(z1[2]), fexp2(z1[3]));
            pb[qt] = pk.v;
            lacc[qt] = MFMA16(onesf, pb[qt], lacc[qt]);   // l partial (wave's keys)
        }

        // ---- O^T += V^T P^T over this wave's 32 keys ----
        #pragma unroll
        for (int d = 0; d < 4; ++d) {
            const bf16x8 av = *(const bf16x8*)&vs[cur][d * 16 + lane4][((kq * 4 + quad) ^ l7) * 8];
            #pragma unroll
            for (int qt = 0; qt < 4; ++qt)
                o[d][qt] = MFMA16(av, pb[qt], o[d][qt]);
        }

        // ---- write-late: staged regs -> other buffer ----
        if (more) {
            #pragma unroll
            for (int s = 0; s < 4; ++s) {
                *(bf16x8*)&ks[cur ^ 1][krow0 + 32 * s][kcol] = kv[s];
                bf16x4 lo = __builtin_shufflevector(vv[s], vv[s], 0, 1, 2, 3);
                bf16x4 hi = __builtin_shufflevector(vv[s], vv[s], 4, 5, 6, 7);
                *(bf16x4*)&vs[cur ^ 1][vrow0 + 16 * s][colA] = lo;
                *(bf16x4*)&vs[cur ^ 1][vrow0 + 16 * s][colB] = hi;
            }
        }
        __syncthreads();
    }

    // ---- epilogue: cross-wave O reduction via LDS overlay ----
    float* pbuf = (float*)smem;   // [w][dh 64][q 64] f32 = 64 KB
    #pragma unroll
    for (int d = 0; d < 4; ++d)
        #pragma unroll
        for (int qt = 0; qt < 4; ++qt)
            #pragma unroll
            for (int r = 0; r < 4; ++r)
                pbuf[(kq * 64 + d * 16 + quad * 4 + r) * 64 + qt * 16 + lane4] = o[d][qt][r];
    __syncthreads();

    // wave kq finalizes q-tile kq (all dh)
    f32x4 of[4];
    #pragma unroll
    for (int d = 0; d < 4; ++d)
        #pragma unroll
        for (int r = 0; r < 4; ++r) {
            const int dh = d * 16 + quad * 4 + r;
            const int qc = kq * 16 + lane4;
            of[d][r] = pbuf[dh * 64 + qc] + pbuf[(64 + dh) * 64 + qc]
                     + pbuf[(128 + dh) * 64 + qc] + pbuf[(192 + dh) * 64 + qc];
        }
    __syncthreads();

    // l exchange (reuse first 1 KB of the overlay after O is consumed)
    if (quad == 0) {
        #pragma unroll
        for (int qt = 0; qt < 4; ++qt)
            pbuf[(kq * 4 + qt) * 16 + lane4] = lacc[qt][0];
    }
    __syncthreads();
    const float lt = pbuf[(0 * 4 + kq) * 16 + lane4] + pbuf[(1 * 4 + kq) * 16 + lane4]
                   + pbuf[(2 * 4 + kq) * 16 + lane4] + pbuf[(3 * 4 + kq) * 16 + lane4];
    const float linv = 1.0f / lt;

    const int b = bh >> 4, h = bh & 15;
    const int n = q0 + kq * 16 + lane4;
    unsigned short* obase = aob + ((size_t)b * NN + n) * INNER + h * DHD;
    #pragma unroll
    for (int d = 0; d < 4; ++d) {
        uint2 pk;
        pk.x = packbf2(of[d][0] * linv, of[d][1] * linv);
        pk.y = packbf2(of[d][2] * linv, of[d][3] * linv);
        *(uint2*)(obase + d * 16 + quad * 4) = pk;
    }
}

// =====================================================================
// Kernel 3: output projection via bf16 MFMA (same T3-min 2-phase loop).
// =====================================================================
__global__ __launch_bounds__(256) void out_proj_mfma(
    const unsigned short* __restrict__ Ab, const unsigned short* __restrict__ Wt,
    const float* __restrict__ bias, float* __restrict__ C)
{
    __shared__ __align__(16) unsigned short As[2][128 * 32];
    __shared__ __align__(16) unsigned short Bs[2][128 * 32];

    const int t     = threadIdx.x;
    const int w     = t >> 6, lane = t & 63;
    const int lane4 = lane & 15, quad = lane >> 4, quad8 = quad * 8;
    const int wm    = w >> 1, wn = w & 1;
    const int m0    = blockIdx.y * 128, n0 = blockIdx.x * 128;

    const int srow = t >> 2, scol = (t & 3) * 8;
    const unsigned short* gA = Ab + (size_t)(m0 + srow) * INNER + scol;
    const unsigned short* gB = Wt + (size_t)(n0 + srow) * INNER + scol;

    f32x4 acc[4][4] = {};

    // prologue: stage k0 = 0 into buf 0
    ASYNC16(gA,               As[0] + t * 8);
    ASYNC16(gA + 64 * INNER,  As[0] + t * 8 + 2048);
    ASYNC16(gB,               Bs[0] + t * 8);
    ASYNC16(gB + 64 * INNER,  Bs[0] + t * 8 + 2048);
    __syncthreads();

    for (int k0 = 0; k0 < INNER; k0 += 32) {
        const int cur = (k0 >> 5) & 1;
        if (k0 + 32 < INNER) {
            ASYNC16(gA + k0 + 32,               As[cur ^ 1] + t * 8);
            ASYNC16(gA + 64 * INNER + k0 + 32,  As[cur ^ 1] + t * 8 + 2048);
            ASYNC16(gB + k0 + 32,               Bs[cur ^ 1] + t * 8);
            ASYNC16(gB + 64 * INNER + k0 + 32,  Bs[cur ^ 1] + t * 8 + 2048);
        }

        bf16x8 a[4], b[4];
        #pragma unroll
        for (int i = 0; i < 4; ++i)
            a[i] = *(const bf16x8*)&As[cur][(wm * 64 + i * 16 + lane4) * 32 + quad8];
        #pragma unroll
        for (int j = 0; j < 4; ++j)
            b[j] = *(const bf16x8*)&Bs[cur][(wn * 64 + j * 16 + lane4) * 32 + quad8];
        #pragma unroll
        for (int i = 0; i < 4; ++i)
            #pragma unroll
            for (int j = 0; j < 4; ++j)
                acc[i][j] = MFMA16(a[i], b[j], acc[i][j]);

        __syncthreads();   // drains vmcnt: buf[cur^1] ready for next iter
    }

    #pragma unroll
    for (int j = 0; j < 4; ++j) {
        const int col = n0 + wn * 64 + j * 16 + lane4;
        const float bv = bias[col];
        #pragma unroll
        for (int i = 0; i < 4; ++i)
            #pragma unroll
            for (int r = 0; r < 4; ++r) {
                const int rg = m0 + wm * 64 + i * 16 + quad * 4 + r;
                C[(size_t)rg * DD + col] = acc[i][j][r] + bv;
            }
    }
}

// =====================================================================
extern "C" void kernel_launch(void* const* d_in, const int* in_sizes, int n_in,
                              void* d_out, int out_size, void* d_ws, size_t ws_size,
                              hipStream_t stream)
{
    const float* X    = (const float*)d_in[0];   // (4,2048,1024)
    const float* Wq   = (const float*)d_in[1];   // (1024,1024)
    const float* Wkv  = (const float*)d_in[2];   // (1024,2048)
    const float* Wout = (const float*)d_in[3];   // (1024,1024)
    const float* bout = (const float*)d_in[4];   // (1024,)
    float* out = (float*)d_out;

    // ws (bf16 elems): qb|kb|vtb|xb(=aob after proj)|WtAll|WoT = 75.5 MB
    const size_t E = (size_t)BB * HH * NN * DHD;   // 8388608
    unsigned short* qb  = (unsigned short*)d_ws;
    unsigned short* kb  = qb + E;
    unsigned short* vtb = kb + E;                // V^T [b][h][dh][n]
    unsigned short* xb  = vtb + E;               // X bf16; later reused as ao
    unsigned short* wt  = xb + E;                // [3072][1024] = WqT ; WkvT
    unsigned short* wo  = wt + (size_t)3072 * 1024;  // [1024][1024]

    cast_x_kernel<<<4096, 256, 0, stream>>>(X, xb);
    tcast_kernel<<<dim3(32, 32), 256, 0, stream>>>(Wq,   wt,               1024, 1024);
    tcast_kernel<<<dim3(64, 32), 256, 0, stream>>>(Wkv,  wt + 1024 * 1024, 1024, 2048);
    tcast_kernel<<<dim3(32, 32), 256, 0, stream>>>(Wout, wo,               1024, 1024);

    proj_qkv_mfma<<<dim3(3072 / 128, 8192 / 128), 256, 0, stream>>>(
        xb, wt, qb, kb, vtb);

    attn_kernel<<<dim3(NN / 64 * BB * HH), 256, 0, stream>>>(qb, kb, vtb, xb);

    out_proj_mfma<<<dim3(1024 / 128, 8192 / 128), 256, 0, stream>>>(
        xb, wo, bout, out);
}

// Round 13
// 298.786 us; speedup vs baseline: 1.2829x; 1.0222x over previous
//
#include <hip/hip_runtime.h>
#include <math.h>

// Problem constants (fixed by reference: b=4, n=2048, d=1024, H=16, DH=64)
#define BB    4
#define NN    2048
#define DD    1024
#define HH    16
#define DHD   64
#define INNER 1024
// log2(10000)/16 for inv_freq = 2^(-f * LOG2_10K_D16)
#define LOG2_10K_D16 0.8304820237218406f
// SCALE * log2(e): folded into Q at projection time -> attn uses raw exp2
#define SCALE_LOG2E 0.1803368801111601f

typedef short bf16x8 __attribute__((ext_vector_type(8)));   // 8 bf16 = 4 VGPRs
typedef short bf16x4 __attribute__((ext_vector_type(4)));   // 4 bf16 = 2 VGPRs
typedef float f32x4  __attribute__((ext_vector_type(4)));
typedef unsigned short u16x8 __attribute__((ext_vector_type(8)));

// async 16B/lane global->LDS (lane i lands at wave-uniform base + i*16)
#define ASYNC16(g, l) __builtin_amdgcn_global_load_lds( \
    (const __attribute__((address_space(1))) void*)(g),  \
    (__attribute__((address_space(3))) void*)(l), 16, 0, 0)

#define MFMA16(a, b, c) __builtin_amdgcn_mfma_f32_16x16x32_bf16((a), (b), (c), 0, 0, 0)

// ---------- fast exp2: raw v_exp_f32, no libm range guard ----------
static __device__ __forceinline__ float fexp2(float x) {
#if __has_builtin(__builtin_amdgcn_exp2f)
    return __builtin_amdgcn_exp2f(x);
#else
    float r;
    asm("v_exp_f32 %0, %1" : "=v"(r) : "v"(x));
    return r;
#endif
}

// ---------- bf16 helpers (manual RNE; no hip_bf16.h dependency) ----------
static __device__ __forceinline__ unsigned short f2bf(float f) {
    union { float f; unsigned int u; } v; v.f = f;
    unsigned int u = v.u;
    u += 0x7fffu + ((u >> 16) & 1u);
    return (unsigned short)(u >> 16);
}
// pack two f32 -> bf16x2 dword, round-half-up via +0x8000 then byte-perm.
static __device__ __forceinline__ unsigned int packbf2(float lo, float hi) {
    union { float f; unsigned int u; } a, b;
    a.f = lo; b.f = hi;
    return __builtin_amdgcn_perm(b.u + 0x8000u, a.u + 0x8000u, 0x07060302u);
}

// =====================================================================
// Pre-pass A: cast X fp32 -> bf16
// =====================================================================
__global__ __launch_bounds__(256) void cast_x_kernel(
    const float* __restrict__ X, unsigned short* __restrict__ Xb)
{
    const size_t i = ((size_t)blockIdx.x * 256 + threadIdx.x) * 8;
    const float4 a = *(const float4*)(X + i);
    const float4 b = *(const float4*)(X + i + 4);
    u16x8 o;
    o[0] = f2bf(a.x); o[1] = f2bf(a.y); o[2] = f2bf(a.z); o[3] = f2bf(a.w);
    o[4] = f2bf(b.x); o[5] = f2bf(b.y); o[6] = f2bf(b.z); o[7] = f2bf(b.w);
    *(u16x8*)(Xb + i) = o;
}

// =====================================================================
// Pre-pass B (fused, R13): transpose-cast all 3 weights in ONE launch.
// id <1024: Wq -> wt ; <3072: Wkv -> wt+1M ; else: Wout -> wo.
// =====================================================================
__global__ __launch_bounds__(256) void tcast_all_kernel(
    const float* __restrict__ Wq, const float* __restrict__ Wkv,
    const float* __restrict__ Wout,
    unsigned short* __restrict__ wt, unsigned short* __restrict__ wo)
{
    __shared__ float ts[32][33];
    int id = blockIdx.x;
    const float* src;
    unsigned short* dst;
    int K, N, bx, by;
    if (id < 1024)      { src = Wq;   dst = wt;               K = 1024; N = 1024; bx = id & 31; by = id >> 5; }
    else if (id < 3072) { id -= 1024; src = Wkv; dst = wt + 1024 * 1024; K = 1024; N = 2048; bx = id & 63; by = id >> 6; }
    else                { id -= 3072; src = Wout; dst = wo;   K = 1024; N = 1024; bx = id & 31; by = id >> 5; }

    const int t = threadIdx.x;
    const int n0 = bx * 32, k0 = by * 32;
    const int r = t >> 5, c = t & 31;
    #pragma unroll
    for (int p = 0; p < 4; ++p)
        ts[r + p * 8][c] = src[(size_t)(k0 + r + p * 8) * N + n0 + c];
    __syncthreads();
    #pragma unroll
    for (int p = 0; p < 4; ++p)
        dst[(size_t)(n0 + r + p * 8) * K + k0 + c] = f2bf(ts[c][r + p * 8]);
}

// =====================================================================
// Kernel 1: QKV projection via bf16 MFMA + fused RoPE + head-split.
// R13: 1D grid + bijective XCD-chunk swizzle (T1, nwg=1536 %8==0):
// each XCD gets a contiguous work-id chunk (~8 consecutive M-rows x
// all 24 N-tiles) -> its A-panels (2 MB) stay L2-resident instead of
// thrashing to L3. 2-phase double-buffered staging (R12) kept.
// =====================================================================
__global__ __launch_bounds__(256) void proj_qkv_mfma(
    const unsigned short* __restrict__ Xb, const unsigned short* __restrict__ Wt,
    unsigned short* __restrict__ qb, unsigned short* __restrict__ kb,
    unsigned short* __restrict__ vb)
{
    __shared__ __align__(16) unsigned short As[2][128 * 32];
    __shared__ __align__(16) unsigned short Bs[2][128 * 32];

    const int t     = threadIdx.x;
    const int w     = t >> 6, lane = t & 63;
    const int lane4 = lane & 15, quad = lane >> 4, quad8 = quad * 8;
    const int wm    = w >> 1, wn = w & 1;

    // XCD-chunk swizzle: work-id = (bid%8)*(1536/8) + bid/8  (bijective)
    const int wid = ((blockIdx.x & 7) * 192) + (blockIdx.x >> 3);
    const int n0  = (wid % 24) * 128;
    const int m0  = (wid / 24) * 128;

    const int srow = t >> 2, scol = (t & 3) * 8;
    const unsigned short* gA = Xb + (size_t)(m0 + srow) * DD + scol;
    const unsigned short* gB = Wt + (size_t)(n0 + srow) * DD + scol;

    f32x4 acc[4][4] = {};

    // prologue: stage k0 = 0 into buf 0
    ASYNC16(gA,            As[0] + t * 8);
    ASYNC16(gA + 64 * DD,  As[0] + t * 8 + 2048);
    ASYNC16(gB,            Bs[0] + t * 8);
    ASYNC16(gB + 64 * DD,  Bs[0] + t * 8 + 2048);
    __syncthreads();

    for (int k0 = 0; k0 < DD; k0 += 32) {
        const int cur = (k0 >> 5) & 1;
        if (k0 + 32 < DD) {
            ASYNC16(gA + k0 + 32,            As[cur ^ 1] + t * 8);
            ASYNC16(gA + 64 * DD + k0 + 32,  As[cur ^ 1] + t * 8 + 2048);
            ASYNC16(gB + k0 + 32,            Bs[cur ^ 1] + t * 8);
            ASYNC16(gB + 64 * DD + k0 + 32,  Bs[cur ^ 1] + t * 8 + 2048);
        }

        bf16x8 a[4], b[4];
        #pragma unroll
        for (int i = 0; i < 4; ++i)
            a[i] = *(const bf16x8*)&As[cur][(wm * 64 + i * 16 + lane4) * 32 + quad8];
        #pragma unroll
        for (int j = 0; j < 4; ++j)
            b[j] = *(const bf16x8*)&Bs[cur][(wn * 64 + j * 16 + lane4) * 32 + quad8];
        #pragma unroll
        for (int i = 0; i < 4; ++i)
            #pragma unroll
            for (int j = 0; j < 4; ++j)
                acc[i][j] = MFMA16(a[i], b[j], acc[i][j]);

        __syncthreads();   // drains vmcnt: buf[cur^1] ready for next iter
    }

    // ---- epilogue ----
    const int sec = n0 >> 10;                  // 0=q 1=k 2=v (uniform/block)

    if (sec == 2) {
        // V: transposed global layout, 4 consecutive n per lane -> uint2
        #pragma unroll
        for (int j = 0; j < 4; ++j) {
            const int csec = (n0 & 1023) + wn * 64 + j * 16;
            const int h    = csec >> 6;
            const int dh   = (csec & 63) + lane4;
            #pragma unroll
            for (int i = 0; i < 4; ++i) {
                const int rg0 = m0 + wm * 64 + i * 16 + quad * 4;
                const int b   = rg0 >> 11;
                const int n   = rg0 & 2047;
                uint2 pk;
                pk.x = packbf2(acc[i][j][0], acc[i][j][1]);
                pk.y = packbf2(acc[i][j][2], acc[i][j][3]);
                *(uint2*)(vb + (((size_t)b * HH + h) * DHD + dh) * NN + n) = pk;
            }
        }
    } else {
        unsigned short* dst = (sec == 0) ? qb : kb;
        const float qscale = (sec == 0) ? SCALE_LOG2E : 1.0f;
        #pragma unroll
        for (int j = 0; j < 4; ++j) {
            const int csec = (n0 & 1023) + wn * 64 + j * 16;
            const int h    = csec >> 6;
            const int dhb  = csec & 63;
            const int dh   = dhb + lane4;
            const bool rope = (dhb < 32);          // wave-uniform
            const float invf = fexp2(-(float)(dh >> 1) * LOG2_10K_D16);
            #pragma unroll
            for (int i = 0; i < 4; ++i) {
                #pragma unroll
                for (int r = 0; r < 4; ++r) {
                    const int rg = m0 + wm * 64 + i * 16 + quad * 4 + r;
                    const int b  = rg >> 11;
                    const int n  = rg & 2047;
                    float x = acc[i][j][r] * qscale;
                    if (rope) {
                        const float ang = (float)n * invf;
                        float s_, c_;
                        __sincosf(ang, &s_, &c_);
                        const float p = __shfl_xor(x, 1);
                        x = (lane4 & 1) ? fmaf(p, s_, x * c_)
                                        : fmaf(p, -s_, x * c_);
                    }
                    dst[(((size_t)b * HH + h) * NN + n) * DHD + dh] = f2bf(x);
                }
            }
        }
    }
}

// =====================================================================
// Kernel 2: flash attention, KEY-SPLIT waves (R4-exact; verified floor
// at 110.4 us / ~625 TF across R5-R11's structural sweep).
// Wave kq owns a key-quarter; Q frags for all 64 queries in regs; P
// stays in registers (S^T MFMA output IS the PV B-frag layout);
// cooperative double-buffered staging, ONE barrier per 128-key tile.
// XCD pinning: id%8 == bh%8 -> K/V L2-resident.
// =====================================================================
__global__ __launch_bounds__(256, 2) void attn_kernel(
    const unsigned short* __restrict__ qb, const unsigned short* __restrict__ kb,
    const unsigned short* __restrict__ vtb, unsigned short* __restrict__ aob)
{
    __shared__ __align__(16) unsigned char smem[65536];
    unsigned short (*ks)[128][64] = (unsigned short (*)[128][64])smem;          // 2x16KB
    unsigned short (*vs)[64][128] = (unsigned short (*)[64][128])(smem + 32768); // 2x16KB

    const int t     = threadIdx.x;
    const int kq    = t >> 6;          // wave's key-quarter
    const int lane  = t & 63;
    const int lane4 = lane & 15;
    const int quad  = lane >> 4;
    const int quad8 = quad * 8;
    const int l7    = lane4 & 7;

    const int bid = blockIdx.x;
    const int bh  = bid & 63;          // id%8 = bh%8 -> per-XCD head groups
    const int q0  = (bid >> 6) * 64;
    const size_t hb = (size_t)bh * NN * DHD;

    // Q B-fragments for ALL 64 queries (held in registers whole kernel)
    bf16x8 qf[4][2];
    #pragma unroll
    for (int qt = 0; qt < 4; ++qt) {
        const unsigned short* qrow = qb + hb + (size_t)(q0 + qt * 16 + lane4) * DHD;
        qf[qt][0] = *(const bf16x8*)(qrow + quad8);
        qf[qt][1] = *(const bf16x8*)(qrow + 32 + quad8);
    }

    // ones A-fragment for the l-accumulating MFMA
    bf16x8 onesf;
    #pragma unroll
    for (int j = 0; j < 8; ++j) onesf[j] = (short)0x3F80;

    // ---- staging geometry (all XOR swizzles are s-invariant) ----
    const int krow0 = t >> 3;
    const int kcol  = ((t & 7) ^ (krow0 & 7)) * 8;
    const unsigned short* kg = kb + hb + (size_t)krow0 * DHD + (t & 7) * 8;
    const int vrow0 = t >> 4;
    const int vm    = t & 15;
    const int vr7   = vrow0 & 7;
    const int vcX   = (vm >> 1) & 3;
    const int vsub  = vm >> 3;
    const int vqA   = (2 * vm) & 3;
    const int vqB   = (2 * vm + 1) & 3;
    const int colA  = (((vcX * 4 + vqA) ^ vr7) * 8) + vsub * 4;
    const int colB  = (((vcX * 4 + vqB) ^ vr7) * 8) + vsub * 4;
    const unsigned short* vg = vtb + hb + (size_t)vrow0 * NN + vm * 8;

    f32x4 o[4][4], lacc[4];
    #pragma unroll
    for (int d = 0; d < 4; ++d)
        #pragma unroll
        for (int qt = 0; qt < 4; ++qt) o[d][qt] = (f32x4){0.f, 0.f, 0.f, 0.f};
    #pragma unroll
    for (int qt = 0; qt < 4; ++qt) lacc[qt] = (f32x4){0.f, 0.f, 0.f, 0.f};

    // ---- prologue: stage tile 0 into buf 0 ----
    {
        bf16x8 kv[4], vv[4];
        #pragma unroll
        for (int s = 0; s < 4; ++s) {
            kv[s] = *(const bf16x8*)(kg + (size_t)s * 32 * DHD);
            vv[s] = *(const bf16x8*)(vg + (size_t)s * 16 * NN);
        }
        #pragma unroll
        for (int s = 0; s < 4; ++s) {
            *(bf16x8*)&ks[0][krow0 + 32 * s][kcol] = kv[s];
            bf16x4 lo = __builtin_shufflevector(vv[s], vv[s], 0, 1, 2, 3);
            bf16x4 hi = __builtin_shufflevector(vv[s], vv[s], 4, 5, 6, 7);
            *(bf16x4*)&vs[0][vrow0 + 16 * s][colA] = lo;
            *(bf16x4*)&vs[0][vrow0 + 16 * s][colB] = hi;
        }
    }
    __syncthreads();

    for (int kt = 0; kt < NN / 128; ++kt) {
        const int cur = kt & 1;
        const bool more = (kt + 1 < NN / 128);

        // issue next tile's global loads (latency hides under compute)
        bf16x8 kv[4], vv[4];
        if (more) {
            #pragma unroll
            for (int s = 0; s < 4; ++s) {
                kv[s] = *(const bf16x8*)(kg + (size_t)(kt + 1) * 128 * DHD + (size_t)s * 32 * DHD);
                vv[s] = *(const bf16x8*)(vg + (kt + 1) * 128 + (size_t)s * 16 * NN);
            }
        }

        // ---- QK A-fragments: this wave's 16 keys per 64-key subtile ----
        bf16x8 ak[2][2];
        #pragma unroll
        for (int sub = 0; sub < 2; ++sub) {
            const int row = sub * 64 + kq * 16 + lane4;
            ak[sub][0] = *(const bf16x8*)&ks[cur][row][(quad ^ l7) * 8];
            ak[sub][1] = *(const bf16x8*)&ks[cur][row][((quad + 4) ^ l7) * 8];
        }

        // ---- S^T -> exp2 -> P B-frags, all in registers ----
        bf16x8 pb[4];
        #pragma unroll
        for (int qt = 0; qt < 4; ++qt) {
            f32x4 z0 = (f32x4){0.f, 0.f, 0.f, 0.f};
            f32x4 z1 = (f32x4){0.f, 0.f, 0.f, 0.f};
            z0 = MFMA16(ak[0][0], qf[qt][0], z0);
            z0 = MFMA16(ak[0][1], qf[qt][1], z0);
            z1 = MFMA16(ak[1][0], qf[qt][0], z1);
            z1 = MFMA16(ak[1][1], qf[qt][1], z1);
            union { unsigned int u[4]; bf16x8 v; } pk;
            pk.u[0] = packbf2(fexp2(z0[0]), fexp2(z0[1]));
            pk.u[1] = packbf2(fexp2(z0[2]), fexp2(z0[3]));
            pk.u[2] = packbf2(fexp2(z1[0]), fexp2(z1[1]));
            pk.u[3] = packbf2(fexp2(z1[2]), fexp2(z1[3]));
            pb[qt] = pk.v;
            lacc[qt] = MFMA16(onesf, pb[qt], lacc[qt]);   // l partial (wave's keys)
        }

        // ---- O^T += V^T P^T over this wave's 32 keys ----
        #pragma unroll
        for (int d = 0; d < 4; ++d) {
            const bf16x8 av = *(const bf16x8*)&vs[cur][d * 16 + lane4][((kq * 4 + quad) ^ l7) * 8];
            #pragma unroll
            for (int qt = 0; qt < 4; ++qt)
                o[d][qt] = MFMA16(av, pb[qt], o[d][qt]);
        }

        // ---- write-late: staged regs -> other buffer ----
        if (more) {
            #pragma unroll
            for (int s = 0; s < 4; ++s) {
                *(bf16x8*)&ks[cur ^ 1][krow0 + 32 * s][kcol] = kv[s];
                bf16x4 lo = __builtin_shufflevector(vv[s], vv[s], 0, 1, 2, 3);
                bf16x4 hi = __builtin_shufflevector(vv[s], vv[s], 4, 5, 6, 7);
                *(bf16x4*)&vs[cur ^ 1][vrow0 + 16 * s][colA] = lo;
                *(bf16x4*)&vs[cur ^ 1][vrow0 + 16 * s][colB] = hi;
            }
        }
        __syncthreads();
    }

    // ---- epilogue: cross-wave O reduction via LDS overlay ----
    float* pbuf = (float*)smem;   // [w][dh 64][q 64] f32 = 64 KB
    #pragma unroll
    for (int d = 0; d < 4; ++d)
        #pragma unroll
        for (int qt = 0; qt < 4; ++qt)
            #pragma unroll
            for (int r = 0; r < 4; ++r)
                pbuf[(kq * 64 + d * 16 + quad * 4 + r) * 64 + qt * 16 + lane4] = o[d][qt][r];
    __syncthreads();

    // wave kq finalizes q-tile kq (all dh)
    f32x4 of[4];
    #pragma unroll
    for (int d = 0; d < 4; ++d)
        #pragma unroll
        for (int r = 0; r < 4; ++r) {
            const int dh = d * 16 + quad * 4 + r;
            const int qc = kq * 16 + lane4;
            of[d][r] = pbuf[dh * 64 + qc] + pbuf[(64 + dh) * 64 + qc]
                     + pbuf[(128 + dh) * 64 + qc] + pbuf[(192 + dh) * 64 + qc];
        }
    __syncthreads();

    // l exchange (reuse first 1 KB of the overlay after O is consumed)
    if (quad == 0) {
        #pragma unroll
        for (int qt = 0; qt < 4; ++qt)
            pbuf[(kq * 4 + qt) * 16 + lane4] = lacc[qt][0];
    }
    __syncthreads();
    const float lt = pbuf[(0 * 4 + kq) * 16 + lane4] + pbuf[(1 * 4 + kq) * 16 + lane4]
                   + pbuf[(2 * 4 + kq) * 16 + lane4] + pbuf[(3 * 4 + kq) * 16 + lane4];
    const float linv = 1.0f / lt;

    const int b = bh >> 4, h = bh & 15;
    const int n = q0 + kq * 16 + lane4;
    unsigned short* obase = aob + ((size_t)b * NN + n) * INNER + h * DHD;
    #pragma unroll
    for (int d = 0; d < 4; ++d) {
        uint2 pk;
        pk.x = packbf2(of[d][0] * linv, of[d][1] * linv);
        pk.y = packbf2(of[d][2] * linv, of[d][3] * linv);
        *(uint2*)(obase + d * 16 + quad * 4) = pk;
    }
}

// =====================================================================
// Kernel 3: output projection via bf16 MFMA (2-phase loop + XCD-chunk
// swizzle: nwg=512 %8==0, chunk=64 -> per-XCD A 2MB + B 2MB fits L2).
// =====================================================================
__global__ __launch_bounds__(256) void out_proj_mfma(
    const unsigned short* __restrict__ Ab, const unsigned short* __restrict__ Wt,
    const float* __restrict__ bias, float* __restrict__ C)
{
    __shared__ __align__(16) unsigned short As[2][128 * 32];
    __shared__ __align__(16) unsigned short Bs[2][128 * 32];

    const int t     = threadIdx.x;
    const int w     = t >> 6, lane = t & 63;
    const int lane4 = lane & 15, quad = lane >> 4, quad8 = quad * 8;
    const int wm    = w >> 1, wn = w & 1;

    const int wid = ((blockIdx.x & 7) * 64) + (blockIdx.x >> 3);
    const int n0  = (wid & 7) * 128;
    const int m0  = (wid >> 3) * 128;

    const int srow = t >> 2, scol = (t & 3) * 8;
    const unsigned short* gA = Ab + (size_t)(m0 + srow) * INNER + scol;
    const unsigned short* gB = Wt + (size_t)(n0 + srow) * INNER + scol;

    f32x4 acc[4][4] = {};

    // prologue: stage k0 = 0 into buf 0
    ASYNC16(gA,               As[0] + t * 8);
    ASYNC16(gA + 64 * INNER,  As[0] + t * 8 + 2048);
    ASYNC16(gB,               Bs[0] + t * 8);
    ASYNC16(gB + 64 * INNER,  Bs[0] + t * 8 + 2048);
    __syncthreads();

    for (int k0 = 0; k0 < INNER; k0 += 32) {
        const int cur = (k0 >> 5) & 1;
        if (k0 + 32 < INNER) {
            ASYNC16(gA + k0 + 32,               As[cur ^ 1] + t * 8);
            ASYNC16(gA + 64 * INNER + k0 + 32,  As[cur ^ 1] + t * 8 + 2048);
            ASYNC16(gB + k0 + 32,               Bs[cur ^ 1] + t * 8);
            ASYNC16(gB + 64 * INNER + k0 + 32,  Bs[cur ^ 1] + t * 8 + 2048);
        }

        bf16x8 a[4], b[4];
        #pragma unroll
        for (int i = 0; i < 4; ++i)
            a[i] = *(const bf16x8*)&As[cur][(wm * 64 + i * 16 + lane4) * 32 + quad8];
        #pragma unroll
        for (int j = 0; j < 4; ++j)
            b[j] = *(const bf16x8*)&Bs[cur][(wn * 64 + j * 16 + lane4) * 32 + quad8];
        #pragma unroll
        for (int i = 0; i < 4; ++i)
            #pragma unroll
            for (int j = 0; j < 4; ++j)
                acc[i][j] = MFMA16(a[i], b[j], acc[i][j]);

        __syncthreads();   // drains vmcnt: buf[cur^1] ready for next iter
    }

    #pragma unroll
    for (int j = 0; j < 4; ++j) {
        const int col = n0 + wn * 64 + j * 16 + lane4;
        const float bv = bias[col];
        #pragma unroll
        for (int i = 0; i < 4; ++i)
            #pragma unroll
            for (int r = 0; r < 4; ++r) {
                const int rg = m0 + wm * 64 + i * 16 + quad * 4 + r;
                C[(size_t)rg * DD + col] = acc[i][j][r] + bv;
            }
    }
}

// =====================================================================
extern "C" void kernel_launch(void* const* d_in, const int* in_sizes, int n_in,
                              void* d_out, int out_size, void* d_ws, size_t ws_size,
                              hipStream_t stream)
{
    const float* X    = (const float*)d_in[0];   // (4,2048,1024)
    const float* Wq   = (const float*)d_in[1];   // (1024,1024)
    const float* Wkv  = (const float*)d_in[2];   // (1024,2048)
    const float* Wout = (const float*)d_in[3];   // (1024,1024)
    const float* bout = (const float*)d_in[4];   // (1024,)
    float* out = (float*)d_out;

    // ws (bf16 elems): qb|kb|vtb|xb(=aob after proj)|WtAll|WoT = 75.5 MB
    const size_t E = (size_t)BB * HH * NN * DHD;   // 8388608
    unsigned short* qb  = (unsigned short*)d_ws;
    unsigned short* kb  = qb + E;
    unsigned short* vtb = kb + E;                // V^T [b][h][dh][n]
    unsigned short* xb  = vtb + E;               // X bf16; later reused as ao
    unsigned short* wt  = xb + E;                // [3072][1024] = WqT ; WkvT
    unsigned short* wo  = wt + (size_t)3072 * 1024;  // [1024][1024]

    cast_x_kernel<<<4096, 256, 0, stream>>>(X, xb);
    tcast_all_kernel<<<4096, 256, 0, stream>>>(Wq, Wkv, Wout, wt, wo);

    proj_qkv_mfma<<<1536, 256, 0, stream>>>(xb, wt, qb, kb, vtb);

    attn_kernel<<<dim3(NN / 64 * BB * HH), 256, 0, stream>>>(qb, kb, vtb, xb);

    out_proj_mfma<<<512, 256, 0, stream>>>(xb, wo, bout, out);
}

// Round 15
// 274.039 us; speedup vs baseline: 1.3987x; 1.0903x over previous
//
#include <hip/hip_runtime.h>
#include <math.h>

// Problem constants (fixed by reference: b=4, n=2048, d=1024, H=16, DH=64)
#define BB    4
#define NN    2048
#define DD    1024
#define HH    16
#define DHD   64
#define INNER 1024
// log2(10000)/16 for inv_freq = 2^(-f * LOG2_10K_D16)
#define LOG2_10K_D16 0.8304820237218406f
// SCALE * log2(e): folded into Q at projection time -> attn uses raw exp2
#define SCALE_LOG2E 0.1803368801111601f

typedef short bf16x8 __attribute__((ext_vector_type(8)));   // 8 bf16 = 4 VGPRs
typedef short bf16x4 __attribute__((ext_vector_type(4)));   // 4 bf16 = 2 VGPRs
typedef float f32x4  __attribute__((ext_vector_type(4)));
typedef unsigned short u16x8 __attribute__((ext_vector_type(8)));

// async 16B/lane global->LDS (lane i lands at wave-uniform base + i*16)
#define ASYNC16(g, l) __builtin_amdgcn_global_load_lds( \
    (const __attribute__((address_space(1))) void*)(g),  \
    (__attribute__((address_space(3))) void*)(l), 16, 0, 0)

#define MFMA16(a, b, c) __builtin_amdgcn_mfma_f32_16x16x32_bf16((a), (b), (c), 0, 0, 0)

// ---------- fast exp2: raw v_exp_f32, no libm range guard ----------
static __device__ __forceinline__ float fexp2(float x) {
#if __has_builtin(__builtin_amdgcn_exp2f)
    return __builtin_amdgcn_exp2f(x);
#else
    float r;
    asm("v_exp_f32 %0, %1" : "=v"(r) : "v"(x));
    return r;
#endif
}

// ---------- bf16 helpers (manual RNE; no hip_bf16.h dependency) ----------
static __device__ __forceinline__ unsigned short f2bf(float f) {
    union { float f; unsigned int u; } v; v.f = f;
    unsigned int u = v.u;
    u += 0x7fffu + ((u >> 16) & 1u);
    return (unsigned short)(u >> 16);
}
// pack two f32 -> bf16x2 dword, round-half-up via +0x8000 then byte-perm.
static __device__ __forceinline__ unsigned int packbf2(float lo, float hi) {
    union { float f; unsigned int u; } a, b;
    a.f = lo; b.f = hi;
    return __builtin_amdgcn_perm(b.u + 0x8000u, a.u + 0x8000u, 0x07060302u);
}

// =====================================================================
// Pre-pass (fused): one launch.
// id < 4096: cast X fp32 -> bf16.  id >= 4096: transpose-cast weights.
// Branch is block-uniform; the cast path returns before any barrier.
// =====================================================================
__global__ __launch_bounds__(256) void prepass_kernel(
    const float* __restrict__ X,
    const float* __restrict__ Wq, const float* __restrict__ Wkv,
    const float* __restrict__ Wout,
    unsigned short* __restrict__ Xb,
    unsigned short* __restrict__ wt, unsigned short* __restrict__ wo)
{
    __shared__ float ts[32][33];
    const int t = threadIdx.x;

    if (blockIdx.x < 4096) {
        const size_t i = ((size_t)blockIdx.x * 256 + t) * 8;
        const float4 a = *(const float4*)(X + i);
        const float4 b = *(const float4*)(X + i + 4);
        u16x8 o;
        o[0] = f2bf(a.x); o[1] = f2bf(a.y); o[2] = f2bf(a.z); o[3] = f2bf(a.w);
        o[4] = f2bf(b.x); o[5] = f2bf(b.y); o[6] = f2bf(b.z); o[7] = f2bf(b.w);
        *(u16x8*)(Xb + i) = o;
        return;
    }

    int id = blockIdx.x - 4096;
    const float* src;
    unsigned short* dst;
    int K, N, bx, by;
    if (id < 1024)      { src = Wq;   dst = wt;               K = 1024; N = 1024; bx = id & 31; by = id >> 5; }
    else if (id < 3072) { id -= 1024; src = Wkv; dst = wt + 1024 * 1024; K = 1024; N = 2048; bx = id & 63; by = id >> 6; }
    else                { id -= 3072; src = Wout; dst = wo;   K = 1024; N = 1024; bx = id & 31; by = id >> 5; }

    const int n0 = bx * 32, k0 = by * 32;
    const int r = t >> 5, c = t & 31;
    #pragma unroll
    for (int p = 0; p < 4; ++p)
        ts[r + p * 8][c] = src[(size_t)(k0 + r + p * 8) * N + n0 + c];
    __syncthreads();
    #pragma unroll
    for (int p = 0; p < 4; ++p)
        dst[(size_t)(n0 + r + p * 8) * K + k0 + c] = f2bf(ts[c][r + p * 8]);
}

// =====================================================================
// Kernel 1: QKV projection via bf16 MFMA + fused RoPE + head-split.
// Q/K epilogue goes through an LDS transpose buffer (the 32 KB
// loop-LDS, free after the K-loop): post-RoPE bf16 values written to
// sm[row][col ^ ((row&7)<<3)] (swizzle touches only bits 3-5 ->
// aligned 8-blocks preserved), then read back as bf16x8 rows -> 8
// coalesced 16-B stores/lane instead of 64 scalar 2-B stores.
// V path keeps its uint2 transposed stores.
// XCD-chunk swizzle (R13) + 2-phase double-buffered staging (R12).
// =====================================================================
__global__ __launch_bounds__(256) void proj_qkv_mfma(
    const unsigned short* __restrict__ Xb, const unsigned short* __restrict__ Wt,
    unsigned short* __restrict__ qb, unsigned short* __restrict__ kb,
    unsigned short* __restrict__ vb)
{
    __shared__ __align__(16) unsigned short sm[16384];   // As[2]|Bs[2] / epi [128][128]
    unsigned short* As0 = sm;           // [2][4096]
    unsigned short* Bs0 = sm + 8192;    // [2][4096]

    const int t     = threadIdx.x;
    const int w     = t >> 6, lane = t & 63;
    const int lane4 = lane & 15, quad = lane >> 4, quad8 = quad * 8;
    const int wm    = w >> 1, wn = w & 1;

    // XCD-chunk swizzle: work-id = (bid%8)*(1536/8) + bid/8  (bijective)
    const int wid = ((blockIdx.x & 7) * 192) + (blockIdx.x >> 3);
    const int n0  = (wid % 24) * 128;
    const int m0  = (wid / 24) * 128;

    const int srow = t >> 2, scol = (t & 3) * 8;
    const unsigned short* gA = Xb + (size_t)(m0 + srow) * DD + scol;
    const unsigned short* gB = Wt + (size_t)(n0 + srow) * DD + scol;

    f32x4 acc[4][4] = {};

    // prologue: stage k0 = 0 into buf 0
    ASYNC16(gA,            As0 + t * 8);
    ASYNC16(gA + 64 * DD,  As0 + t * 8 + 2048);
    ASYNC16(gB,            Bs0 + t * 8);
    ASYNC16(gB + 64 * DD,  Bs0 + t * 8 + 2048);
    __syncthreads();

    for (int k0 = 0; k0 < DD; k0 += 32) {
        const int cur = (k0 >> 5) & 1;
        if (k0 + 32 < DD) {
            ASYNC16(gA + k0 + 32,            As0 + (cur ^ 1) * 4096 + t * 8);
            ASYNC16(gA + 64 * DD + k0 + 32,  As0 + (cur ^ 1) * 4096 + t * 8 + 2048);
            ASYNC16(gB + k0 + 32,            Bs0 + (cur ^ 1) * 4096 + t * 8);
            ASYNC16(gB + 64 * DD + k0 + 32,  Bs0 + (cur ^ 1) * 4096 + t * 8 + 2048);
        }

        bf16x8 a[4], b[4];
        #pragma unroll
        for (int i = 0; i < 4; ++i)
            a[i] = *(const bf16x8*)&As0[cur * 4096 + (wm * 64 + i * 16 + lane4) * 32 + quad8];
        #pragma unroll
        for (int j = 0; j < 4; ++j)
            b[j] = *(const bf16x8*)&Bs0[cur * 4096 + (wn * 64 + j * 16 + lane4) * 32 + quad8];
        #pragma unroll
        for (int i = 0; i < 4; ++i)
            #pragma unroll
            for (int j = 0; j < 4; ++j)
                acc[i][j] = MFMA16(a[i], b[j], acc[i][j]);

        __syncthreads();   // drains vmcnt: buf[cur^1] ready for next iter
    }

    // ---- epilogue ----
    const int sec = n0 >> 10;                  // 0=q 1=k 2=v (uniform/block)

    if (sec == 2) {
        // V: transposed global layout, 4 consecutive n per lane -> uint2
        #pragma unroll
        for (int j = 0; j < 4; ++j) {
            const int csec = (n0 & 1023) + wn * 64 + j * 16;
            const int h    = csec >> 6;
            const int dh   = (csec & 63) + lane4;
            #pragma unroll
            for (int i = 0; i < 4; ++i) {
                const int rg0 = m0 + wm * 64 + i * 16 + quad * 4;
                const int b   = rg0 >> 11;
                const int n   = rg0 & 2047;
                uint2 pk;
                pk.x = packbf2(acc[i][j][0], acc[i][j][1]);
                pk.y = packbf2(acc[i][j][2], acc[i][j][3]);
                *(uint2*)(vb + (((size_t)b * HH + h) * DHD + dh) * NN + n) = pk;
            }
        }
    } else {
        unsigned short* dst = (sec == 0) ? qb : kb;
        const float qscale = (sec == 0) ? SCALE_LOG2E : 1.0f;

        // phase 1: RoPE + pack into LDS transpose buffer (swizzled)
        #pragma unroll
        for (int j = 0; j < 4; ++j) {
            const int csec = (n0 & 1023) + wn * 64 + j * 16;
            const int dhb  = csec & 63;
            const int dh   = dhb + lane4;
            const bool rope = (dhb < 32);          // wave-uniform
            const float invf = fexp2(-(float)(dh >> 1) * LOG2_10K_D16);
            const int col  = wn * 64 + j * 16 + lane4;
            #pragma unroll
            for (int i = 0; i < 4; ++i) {
                #pragma unroll
                for (int r = 0; r < 4; ++r) {
                    const int row = wm * 64 + i * 16 + quad * 4 + r;
                    const int n   = (m0 & 2047) + row;
                    float x = acc[i][j][r] * qscale;
                    if (rope) {
                        const float ang = (float)n * invf;
                        float s_, c_;
                        __sincosf(ang, &s_, &c_);
                        const float p = __shfl_xor(x, 1);
                        x = (lane4 & 1) ? fmaf(p, s_, x * c_)
                                        : fmaf(p, -s_, x * c_);
                    }
                    sm[row * 128 + (col ^ ((row & 7) << 3))] = f2bf(x);
                }
            }
        }
        __syncthreads();

        // phase 2: coalesced b128 stores (8 per lane)
        const int b     = m0 >> 11;
        const int hbase = (n0 & 1023) >> 6;
        #pragma unroll
        for (int s = 0; s < 8; ++s) {
            const int flat = s * 256 + t;
            const int row  = flat >> 4;        // 0..127
            const int cg   = flat & 15;        // 0..15 (8-col group)
            const int n    = (m0 & 2047) + row;
            const int h    = hbase + (cg >> 3);
            const int dh0  = (cg & 7) * 8;
            const bf16x8 v = *(const bf16x8*)&sm[row * 128 + ((cg * 8) ^ ((row & 7) << 3))];
            *(bf16x8*)(dst + (((size_t)b * HH + h) * NN + n) * DHD + dh0) = v;
        }
    }
}

// =====================================================================
// Kernel 2: flash attention, KEY-SPLIT waves (R4-exact; verified floor
// at ~110 us / ~625 TF across the R5-R11 structural sweep).
// Wave kq owns a key-quarter; Q frags for all 64 queries in regs; P
// stays in registers (S^T MFMA output IS the PV B-frag layout);
// cooperative double-buffered staging, ONE barrier per 128-key tile.
// XCD pinning: id%8 == bh%8 -> K/V L2-resident.
// =====================================================================
__global__ __launch_bounds__(256, 2) void attn_kernel(
    const unsigned short* __restrict__ qb, const unsigned short* __restrict__ kb,
    const unsigned short* __restrict__ vtb, unsigned short* __restrict__ aob)
{
    __shared__ __align__(16) unsigned char smem[65536];
    unsigned short (*ks)[128][64] = (unsigned short (*)[128][64])smem;          // 2x16KB
    unsigned short (*vs)[64][128] = (unsigned short (*)[64][128])(smem + 32768); // 2x16KB

    const int t     = threadIdx.x;
    const int kq    = t >> 6;          // wave's key-quarter
    const int lane  = t & 63;
    const int lane4 = lane & 15;
    const int quad  = lane >> 4;
    const int quad8 = quad * 8;
    const int l7    = lane4 & 7;

    const int bid = blockIdx.x;
    const int bh  = bid & 63;          // id%8 = bh%8 -> per-XCD head groups
    const int q0  = (bid >> 6) * 64;
    const size_t hb = (size_t)bh * NN * DHD;

    // Q B-fragments for ALL 64 queries (held in registers whole kernel)
    bf16x8 qf[4][2];
    #pragma unroll
    for (int qt = 0; qt < 4; ++qt) {
        const unsigned short* qrow = qb + hb + (size_t)(q0 + qt * 16 + lane4) * DHD;
        qf[qt][0] = *(const bf16x8*)(qrow + quad8);
        qf[qt][1] = *(const bf16x8*)(qrow + 32 + quad8);
    }

    // ones A-fragment for the l-accumulating MFMA
    bf16x8 onesf;
    #pragma unroll
    for (int j = 0; j < 8; ++j) onesf[j] = (short)0x3F80;

    // ---- staging geometry (all XOR swizzles are s-invariant) ----
    const int krow0 = t >> 3;
    const int kcol  = ((t & 7) ^ (krow0 & 7)) * 8;
    const unsigned short* kg = kb + hb + (size_t)krow0 * DHD + (t & 7) * 8;
    const int vrow0 = t >> 4;
    const int vm    = t & 15;
    const int vr7   = vrow0 & 7;
    const int vcX   = (vm >> 1) & 3;
    const int vsub  = vm >> 3;
    const int vqA   = (2 * vm) & 3;
    const int vqB   = (2 * vm + 1) & 3;
    const int colA  = (((vcX * 4 + vqA) ^ vr7) * 8) + vsub * 4;
    const int colB  = (((vcX * 4 + vqB) ^ vr7) * 8) + vsub * 4;
    const unsigned short* vg = vtb + hb + (size_t)vrow0 * NN + vm * 8;

    f32x4 o[4][4], lacc[4];
    #pragma unroll
    for (int d = 0; d < 4; ++d)
        #pragma unroll
        for (int qt = 0; qt < 4; ++qt) o[d][qt] = (f32x4){0.f, 0.f, 0.f, 0.f};
    #pragma unroll
    for (int qt = 0; qt < 4; ++qt) lacc[qt] = (f32x4){0.f, 0.f, 0.f, 0.f};

    // ---- prologue: stage tile 0 into buf 0 ----
    {
        bf16x8 kv[4], vv[4];
        #pragma unroll
        for (int s = 0; s < 4; ++s) {
            kv[s] = *(const bf16x8*)(kg + (size_t)s * 32 * DHD);
            vv[s] = *(const bf16x8*)(vg + (size_t)s * 16 * NN);
        }
        #pragma unroll
        for (int s = 0; s < 4; ++s) {
            *(bf16x8*)&ks[0][krow0 + 32 * s][kcol] = kv[s];
            bf16x4 lo = __builtin_shufflevector(vv[s], vv[s], 0, 1, 2, 3);
            bf16x4 hi = __builtin_shufflevector(vv[s], vv[s], 4, 5, 6, 7);
            *(bf16x4*)&vs[0][vrow0 + 16 * s][colA] = lo;
            *(bf16x4*)&vs[0][vrow0 + 16 * s][colB] = hi;
        }
    }
    __syncthreads();

    for (int kt = 0; kt < NN / 128; ++kt) {
        const int cur = kt & 1;
        const bool more = (kt + 1 < NN / 128);

        // issue next tile's global loads (latency hides under compute)
        bf16x8 kv[4], vv[4];
        if (more) {
            #pragma unroll
            for (int s = 0; s < 4; ++s) {
                kv[s] = *(const bf16x8*)(kg + (size_t)(kt + 1) * 128 * DHD + (size_t)s * 32 * DHD);
                vv[s] = *(const bf16x8*)(vg + (kt + 1) * 128 + (size_t)s * 16 * NN);
            }
        }

        // ---- QK A-fragments: this wave's 16 keys per 64-key subtile ----
        bf16x8 ak[2][2];
        #pragma unroll
        for (int sub = 0; sub < 2; ++sub) {
            const int row = sub * 64 + kq * 16 + lane4;
            ak[sub][0] = *(const bf16x8*)&ks[cur][row][(quad ^ l7) * 8];
            ak[sub][1] = *(const bf16x8*)&ks[cur][row][((quad + 4) ^ l7) * 8];
        }

        // ---- S^T -> exp2 -> P B-frags, all in registers ----
        bf16x8 pb[4];
        #pragma unroll
        for (int qt = 0; qt < 4; ++qt) {
            f32x4 z0 = (f32x4){0.f, 0.f, 0.f, 0.f};
            f32x4 z1 = (f32x4){0.f, 0.f, 0.f, 0.f};
            z0 = MFMA16(ak[0][0], qf[qt][0], z0);
            z0 = MFMA16(ak[0][1], qf[qt][1], z0);
            z1 = MFMA16(ak[1][0], qf[qt][0], z1);
            z1 = MFMA16(ak[1][1], qf[qt][1], z1);
            union { unsigned int u[4]; bf16x8 v; } pk;
            pk.u[0] = packbf2(fexp2(z0[0]), fexp2(z0[1]));
            pk.u[1] = packbf2(fexp2(z0[2]), fexp2(z0[3]));
            pk.u[2] = packbf2(fexp2(z1[0]), fexp2(z1[1]));
            pk.u[3] = packbf2(fexp2(z1[2]), fexp2(z1[3]));
            pb[qt] = pk.v;
            lacc[qt] = MFMA16(onesf, pb[qt], lacc[qt]);   // l partial (wave's keys)
        }

        // ---- O^T += V^T P^T over this wave's 32 keys ----
        #pragma unroll
        for (int d = 0; d < 4; ++d) {
            const bf16x8 av = *(const bf16x8*)&vs[cur][d * 16 + lane4][((kq * 4 + quad) ^ l7) * 8];
            #pragma unroll
            for (int qt = 0; qt < 4; ++qt)
                o[d][qt] = MFMA16(av, pb[qt], o[d][qt]);
        }

        // ---- write-late: staged regs -> other buffer ----
        if (more) {
            #pragma unroll
            for (int s = 0; s < 4; ++s) {
                *(bf16x8*)&ks[cur ^ 1][krow0 + 32 * s][kcol] = kv[s];
                bf16x4 lo = __builtin_shufflevector(vv[s], vv[s], 0, 1, 2, 3);
                bf16x4 hi = __builtin_shufflevector(vv[s], vv[s], 4, 5, 6, 7);
                *(bf16x4*)&vs[cur ^ 1][vrow0 + 16 * s][colA] = lo;
                *(bf16x4*)&vs[cur ^ 1][vrow0 + 16 * s][colB] = hi;
            }
        }
        __syncthreads();
    }

    // ---- epilogue: cross-wave O reduction via LDS overlay ----
    float* pbuf = (float*)smem;   // [w][dh 64][q 64] f32 = 64 KB
    #pragma unroll
    for (int d = 0; d < 4; ++d)
        #pragma unroll
        for (int qt = 0; qt < 4; ++qt)
            #pragma unroll
            for (int r = 0; r < 4; ++r)
                pbuf[(kq * 64 + d * 16 + quad * 4 + r) * 64 + qt * 16 + lane4] = o[d][qt][r];
    __syncthreads();

    // wave kq finalizes q-tile kq (all dh)
    f32x4 of[4];
    #pragma unroll
    for (int d = 0; d < 4; ++d)
        #pragma unroll
        for (int r = 0; r < 4; ++r) {
            const int dh = d * 16 + quad * 4 + r;
            const int qc = kq * 16 + lane4;
            of[d][r] = pbuf[dh * 64 + qc] + pbuf[(64 + dh) * 64 + qc]
                     + pbuf[(128 + dh) * 64 + qc] + pbuf[(192 + dh) * 64 + qc];
        }
    __syncthreads();

    // l exchange (reuse first 1 KB of the overlay after O is consumed)
    if (quad == 0) {
        #pragma unroll
        for (int qt = 0; qt < 4; ++qt)
            pbuf[(kq * 4 + qt) * 16 + lane4] = lacc[qt][0];
    }
    __syncthreads();
    const float lt = pbuf[(0 * 4 + kq) * 16 + lane4] + pbuf[(1 * 4 + kq) * 16 + lane4]
                   + pbuf[(2 * 4 + kq) * 16 + lane4] + pbuf[(3 * 4 + kq) * 16 + lane4];
    const float linv = 1.0f / lt;

    const int b = bh >> 4, h = bh & 15;
    const int n = q0 + kq * 16 + lane4;
    unsigned short* obase = aob + ((size_t)b * NN + n) * INNER + h * DHD;
    #pragma unroll
    for (int d = 0; d < 4; ++d) {
        uint2 pk;
        pk.x = packbf2(of[d][0] * linv, of[d][1] * linv);
        pk.y = packbf2(of[d][2] * linv, of[d][3] * linv);
        *(uint2*)(obase + d * 16 + quad * 4) = pk;
    }
}

// =====================================================================
// Kernel 3: output projection via bf16 MFMA (2-phase loop + XCD-chunk
// swizzle; unchanged from R13).
// =====================================================================
__global__ __launch_bounds__(256) void out_proj_mfma(
    const unsigned short* __restrict__ Ab, const unsigned short* __restrict__ Wt,
    const float* __restrict__ bias, float* __restrict__ C)
{
    __shared__ __align__(16) unsigned short As[2][128 * 32];
    __shared__ __align__(16) unsigned short Bs[2][128 * 32];

    const int t     = threadIdx.x;
    const int w     = t >> 6, lane = t & 63;
    const int lane4 = lane & 15, quad = lane >> 4, quad8 = quad * 8;
    const int wm    = w >> 1, wn = w & 1;

    const int wid = ((blockIdx.x & 7) * 64) + (blockIdx.x >> 3);
    const int n0  = (wid & 7) * 128;
    const int m0  = (wid >> 3) * 128;

    const int srow = t >> 2, scol = (t & 3) * 8;
    const unsigned short* gA = Ab + (size_t)(m0 + srow) * INNER + scol;
    const unsigned short* gB = Wt + (size_t)(n0 + srow) * INNER + scol;

    f32x4 acc[4][4] = {};

    // prologue: stage k0 = 0 into buf 0
    ASYNC16(gA,               As[0] + t * 8);
    ASYNC16(gA + 64 * INNER,  As[0] + t * 8 + 2048);
    ASYNC16(gB,               Bs[0] + t * 8);
    ASYNC16(gB + 64 * INNER,  Bs[0] + t * 8 + 2048);
    __syncthreads();

    for (int k0 = 0; k0 < INNER; k0 += 32) {
        const int cur = (k0 >> 5) & 1;
        if (k0 + 32 < INNER) {
            ASYNC16(gA + k0 + 32,               As[cur ^ 1] + t * 8);
            ASYNC16(gA + 64 * INNER + k0 + 32,  As[cur ^ 1] + t * 8 + 2048);
            ASYNC16(gB + k0 + 32,               Bs[cur ^ 1] + t * 8);
            ASYNC16(gB + 64 * INNER + k0 + 32,  Bs[cur ^ 1] + t * 8 + 2048);
        }

        bf16x8 a[4], b[4];
        #pragma unroll
        for (int i = 0; i < 4; ++i)
            a[i] = *(const bf16x8*)&As[cur][(wm * 64 + i * 16 + lane4) * 32 + quad8];
        #pragma unroll
        for (int j = 0; j < 4; ++j)
            b[j] = *(const bf16x8*)&Bs[cur][(wn * 64 + j * 16 + lane4) * 32 + quad8];
        #pragma unroll
        for (int i = 0; i < 4; ++i)
            #pragma unroll
            for (int j = 0; j < 4; ++j)
                acc[i][j] = MFMA16(a[i], b[j], acc[i][j]);

        __syncthreads();   // drains vmcnt: buf[cur^1] ready for next iter
    }

    #pragma unroll
    for (int j = 0; j < 4; ++j) {
        const int col = n0 + wn * 64 + j * 16 + lane4;
        const float bv = bias[col];
        #pragma unroll
        for (int i = 0; i < 4; ++i)
            #pragma unroll
            for (int r = 0; r < 4; ++r) {
                const int rg = m0 + wm * 64 + i * 16 + quad * 4 + r;
                C[(size_t)rg * DD + col] = acc[i][j][r] + bv;
            }
    }
}

// =====================================================================
extern "C" void kernel_launch(void* const* d_in, const int* in_sizes, int n_in,
                              void* d_out, int out_size, void* d_ws, size_t ws_size,
                              hipStream_t stream)
{
    const float* X    = (const float*)d_in[0];   // (4,2048,1024)
    const float* Wq   = (const float*)d_in[1];   // (1024,1024)
    const float* Wkv  = (const float*)d_in[2];   // (1024,2048)
    const float* Wout = (const float*)d_in[3];   // (1024,1024)
    const float* bout = (const float*)d_in[4];   // (1024,)
    float* out = (float*)d_out;

    // ws (bf16 elems): qb|kb|vtb|xb(=aob after proj)|WtAll|WoT = 75.5 MB
    const size_t E = (size_t)BB * HH * NN * DHD;   // 8388608
    unsigned short* qb  = (unsigned short*)d_ws;
    unsigned short* kb  = qb + E;
    unsigned short* vtb = kb + E;                // V^T [b][h][dh][n]
    unsigned short* xb  = vtb + E;               // X bf16; later reused as ao
    unsigned short* wt  = xb + E;                // [3072][1024] = WqT ; WkvT
    unsigned short* wo  = wt + (size_t)3072 * 1024;  // [1024][1024]

    prepass_kernel<<<8192, 256, 0, stream>>>(X, Wq, Wkv, Wout, xb, wt, wo);

    proj_qkv_mfma<<<1536, 256, 0, stream>>>(xb, wt, qb, kb, vtb);

    attn_kernel<<<dim3(NN / 64 * BB * HH), 256, 0, stream>>>(qb, kb, vtb, xb);

    out_proj_mfma<<<512, 256, 0, stream>>>(xb, wo, bout, out);
}